// Round 10
// baseline (367.224 us; speedup 1.0000x reference)
//
#include <hip/hip_runtime.h>
#include <hip/hip_bf16.h>
#include <math.h>

#define Lnum 3
#define Mdim 4096
#define Pdim 4
#define Gdim 4
#define NIN 8192
#define NOUT 1000
#define Bdim 2048
#define Fdim 6
#define CIN 2048      // input channels per group (all layers)
#define MG 1024       // M / G
#define CH 2048       // M / K
#define DNEXT 8192
#define NRCHUNK (Bdim / 128)   // 16 row-blocks of 128 = GEMM tile rows

typedef short bf16x8 __attribute__((ext_vector_type(8)));
typedef float f32x4 __attribute__((ext_vector_type(4)));

__device__ __forceinline__ short f2bf(float f) {
    union { float f; unsigned u; } v; v.f = f;
    unsigned u = v.u;
    unsigned r = (u + 0x7fffu + ((u >> 16) & 1u)) >> 16;
    return (short)r;
}
__device__ __forceinline__ float bf2f(short h) {
    union { unsigned u; float f; } x;
    x.u = ((unsigned)(unsigned short)h) << 16;
    return x.f;
}

// ---------------------------------------------------------------------------
// x (B x 8192) f32 -> grouped bf16 planes hg[g][b][c] = x[b][4c+g]
__global__ __launch_bounds__(256) void x_to_grouped(
    const float* __restrict__ x, short* __restrict__ hg)
{
    const int c = blockIdx.x * 256 + threadIdx.x;
    const int b = blockIdx.y;
    float4 v = *(const float4*)(x + (size_t)b * NIN + 4 * c);
    const size_t plane = (size_t)Bdim * CIN;
    hg[0 * plane + (size_t)b * CIN + c] = f2bf(v.x);
    hg[1 * plane + (size_t)b * CIN + c] = f2bf(v.y);
    hg[2 * plane + (size_t)b * CIN + c] = f2bf(v.z);
    hg[3 * plane + (size_t)b * CIN + c] = f2bf(v.w);
}

// perm value remap: original j -> grouped col jg = (j&3)*1024 + (j>>2),
// then fold the combinact LDS bank swizzle: js = jg ^ ((jg>>3)&3).
__global__ __launch_bounds__(256) void remap_perms(
    const int* __restrict__ perm, int* __restrict__ perm_g, int n)
{
    int i = blockIdx.x * 256 + threadIdx.x;
    if (i >= n) return;
    int j  = perm[i];
    int jg = ((j & 3) << 10) | (j >> 2);
    perm_g[i] = jg ^ ((jg >> 3) & 3);
}

// ---------------------------------------------------------------------------
// MFMA bf16 GEMM. A: bf16 via global_load_lds (pre-swizzled source). B: f32
// read directly from the input weights, converted to bf16 in-register, written
// to swizzled LDS (reg-staging). Double-buffered, BK=64. Tile 128x128, 8 waves.
// B rows clamped to < bclamp (out-GEMM pad band; those cols never stored).
// If STATS: per-column partial sum/sumsq -> psum/psumsq[by*Mdim + g*sgz + n0+col].
// ---------------------------------------------------------------------------
template<int BN_T, int NWARP, bool STATS, typename CT>
__global__ __launch_bounds__(NWARP * 64) void gemm_mfma(
    const short* __restrict__ A0, size_t aZ, int lda,
    const float* __restrict__ B0, size_t bZ, int ldb, int bclamp,
    const float* __restrict__ bias0, size_t biasZ,
    CT* __restrict__ C0, size_t cZ,
    int K, int ldc, int nbound,
    float* __restrict__ psum, float* __restrict__ psumsq, int sgz)
{
    constexpr int NT   = NWARP * 64;
    constexpr int WCN  = NWARP / 2;       // waves along N
    constexpr int WCOL = BN_T / WCN;      // cols per wave
    constexpr int FN   = WCOL / 16;       // 16-col frags per wave

    // XCD-aware swizzle (nwg % 8 == 0 in all our launches)
    const int nx = gridDim.x, ny = gridDim.y;
    const int nwg = nx * ny * gridDim.z;
    const int lin = blockIdx.x + nx * (blockIdx.y + ny * blockIdx.z);
    int swz = (lin & 7) * (nwg >> 3) + (lin >> 3);
    const int bx = swz % nx; swz /= nx;
    const int by = swz % ny;
    const int g  = swz / ny;

    const short* A  = A0 + aZ * g;
    const float* Bf = B0 + bZ * g;
    CT* C = C0 + cZ * g;

    const int n0 = bx * BN_T;
    const int b0 = by * 128;

    __shared__ short As[2][128 * 64];
    __shared__ short Bs[2][BN_T * 64];

    const int tid  = threadIdx.x;
    const int w    = tid >> 6;
    const int lane = tid & 63;
    const int wr = w / WCN, wc = w % WCN;

    f32x4 acc[4][FN];
#pragma unroll
    for (int m = 0; m < 4; ++m)
#pragma unroll
        for (int n = 0; n < FN; ++n) acc[m][n] = (f32x4)0.f;

    // A-half staging: linear LDS dest, XOR-swizzled global source slot.
    auto stageA = [&](int buf, int k0) {
#pragma unroll
        for (int idx = tid; idx < 128 * 8; idx += NT) {
            const int r = idx >> 3, slot = idx & 7;
            const int gs = slot ^ (r & 7);
            const short* ga = A + (size_t)(b0 + r) * lda + k0 + gs * 8;
            __builtin_amdgcn_global_load_lds(
                (const __attribute__((address_space(1))) void*)ga,
                (__attribute__((address_space(3))) void*)(&As[buf][idx * 8]), 16, 0, 0);
        }
    };

    // B-half: f32 global -> regs. Each thread owns row r = tid>>2, col-quarter
    // q = tid&3 (16 cols). (NT == BN_T*4 required: 512 == 128*4.)
    static_assert(NT == BN_T * 4, "B-staging mapping assumes 4 threads/row");
    const int brow = tid >> 2;
    const int bq   = tid & 3;
    float4 br0, br1, br2, br3;
    auto issueB = [&](int k0) {
        const int rr = min(n0 + brow, bclamp - 1);
        const float* p = Bf + (size_t)rr * ldb + k0 + bq * 16;
        br0 = *(const float4*)(p);
        br1 = *(const float4*)(p + 4);
        br2 = *(const float4*)(p + 8);
        br3 = *(const float4*)(p + 12);
    };
    // cvt + swizzled LDS write (physical slot = logical slot ^ (row&7))
    auto writeB = [&](int buf) {
        bf16x8 o0, o1;
        o0[0] = f2bf(br0.x); o0[1] = f2bf(br0.y); o0[2] = f2bf(br0.z); o0[3] = f2bf(br0.w);
        o0[4] = f2bf(br1.x); o0[5] = f2bf(br1.y); o0[6] = f2bf(br1.z); o0[7] = f2bf(br1.w);
        o1[0] = f2bf(br2.x); o1[1] = f2bf(br2.y); o1[2] = f2bf(br2.z); o1[3] = f2bf(br2.w);
        o1[4] = f2bf(br3.x); o1[5] = f2bf(br3.y); o1[6] = f2bf(br3.z); o1[7] = f2bf(br3.w);
        const int s0 = (2 * bq)     ^ (brow & 7);
        const int s1 = (2 * bq + 1) ^ (brow & 7);
        *(bf16x8*)(&Bs[buf][brow * 64 + s0 * 8]) = o0;
        *(bf16x8*)(&Bs[buf][brow * 64 + s1 * 8]) = o1;
    };

    const int fr15 = lane & 15;
    const int fq   = lane >> 4;

    auto compute = [&](int buf) {
#pragma unroll
        for (int kk = 0; kk < 2; ++kk) {
            bf16x8 af[4], bff[FN];
            const int kob = kk * 64 + fq * 16;
#pragma unroll
            for (int m = 0; m < 4; ++m) {
                const int r  = wr * 64 + m * 16 + fr15;
                const int sw = kob ^ ((r & 7) << 4);
                af[m] = *(const bf16x8*)(&As[buf][r * 64 + (sw >> 1)]);
            }
#pragma unroll
            for (int n = 0; n < FN; ++n) {
                const int r  = wc * WCOL + n * 16 + fr15;
                const int sw = kob ^ ((r & 7) << 4);
                bff[n] = *(const bf16x8*)(&Bs[buf][r * 64 + (sw >> 1)]);
            }
#pragma unroll
            for (int m = 0; m < 4; ++m)
#pragma unroll
                for (int n = 0; n < FN; ++n)
                    acc[m][n] = __builtin_amdgcn_mfma_f32_16x16x32_bf16(af[m], bff[n], acc[m][n], 0, 0, 0);
        }
    };

    // Prologue
    stageA(0, 0);
    issueB(0);
    asm volatile("s_waitcnt vmcnt(0)" ::: "memory");
    writeB(0);
    asm volatile("s_waitcnt lgkmcnt(0)" ::: "memory");
    __builtin_amdgcn_s_barrier();
    asm volatile("" ::: "memory");

    const int nt = K >> 6;
    int p = 0;
    for (int t = 0; t < nt; ++t) {
        if (t + 1 < nt) { stageA(p ^ 1, (t + 1) << 6); issueB((t + 1) << 6); }
        compute(p);
        if (t + 1 < nt) {
            asm volatile("s_waitcnt vmcnt(0)" ::: "memory");
            writeB(p ^ 1);
        }
        asm volatile("s_waitcnt lgkmcnt(0)" ::: "memory");
        __builtin_amdgcn_s_barrier();
        asm volatile("" ::: "memory");
        p ^= 1;
    }

    float s[FN], ss[FN];
#pragma unroll
    for (int n = 0; n < FN; ++n) { s[n] = 0.f; ss[n] = 0.f; }

#pragma unroll
    for (int m = 0; m < 4; ++m) {
#pragma unroll
        for (int n = 0; n < FN; ++n) {
#pragma unroll
            for (int j = 0; j < 4; ++j) {
                const int row = b0 + wr * 64 + m * 16 + fq * 4 + j;
                const int col = n0 + wc * WCOL + n * 16 + fr15;
                if (col < nbound) {
                    float v = acc[m][n][j];
                    if (bias0) v += bias0[biasZ * g + col];
                    C[(size_t)row * ldc + col] = (CT)(sizeof(CT) == 2 ? (CT)f2bf(v) : (CT)v);
                    if (STATS) { s[n] += v; ss[n] += v * v; }
                }
            }
        }
    }

    if (STATS) {
        __syncthreads();   // all waves done with LDS compute buffers
        float* sum_lds = (float*)&As[0][0];
        float* ssq_lds = sum_lds + BN_T * 8;
        const int slot = wr * 4 + fq;
#pragma unroll
        for (int n = 0; n < FN; ++n) {
            const int cl = wc * WCOL + n * 16 + fr15;
            sum_lds[cl * 8 + slot] = s[n];
            ssq_lds[cl * 8 + slot] = ss[n];
        }
        __syncthreads();
        for (int cl = tid; cl < BN_T; cl += NT) {
            float a = 0.f, b = 0.f;
#pragma unroll
            for (int q = 0; q < 8; ++q) {
                a += sum_lds[cl * 8 + q];
                b += ssq_lds[cl * 8 + q];
            }
            const size_t o = (size_t)by * Mdim + g * sgz + n0 + cl;
            psum[o]   = a;
            psumsq[o] = b;
        }
    }
}

// out[b,n] = sum_z p[z][b,n] + bo[n], 4 split-K partials
__global__ __launch_bounds__(256) void reduce_out(
    const float* __restrict__ part, const float* __restrict__ bo,
    float* __restrict__ out)
{
    const int n = blockIdx.x * 256 + threadIdx.x;
    const int b = blockIdx.y;
    if (n >= NOUT) return;
    const size_t S = (size_t)Bdim * 1024;
    const size_t i = (size_t)b * 1024 + n;
    out[(size_t)b * NOUT + n] =
        part[i] + part[S + i] + part[2 * S + i] + part[3 * S + i] + bo[n];
}

// ---------------------------------------------------------------------------
// Columns are in GROUPED order jg = g*1024+m  (orig j = (jg&1023)*4 + jg>>10)
__global__ __launch_bounds__(256) void bn_finalize(
    const float* __restrict__ psum, const float* __restrict__ psumsq,
    const float* __restrict__ gamma, const float* __restrict__ beta,
    float* __restrict__ scale, float* __restrict__ shift)
{
    const int jg = blockIdx.x * 256 + threadIdx.x;
    if (jg >= Mdim) return;
    const int j = ((jg & 1023) << 2) | (jg >> 10);
    float s = 0.f, ss = 0.f;
    for (int r = 0; r < NRCHUNK; ++r) {
        s  += psum[r * Mdim + jg];
        ss += psumsq[r * Mdim + jg];
    }
    const float mu  = s * (1.f / Bdim);
    const float var = ss * (1.f / Bdim) - mu * mu;
    const float sc  = gamma[j] * rsqrtf(var + 1e-5f);
    scale[jg] = sc;
    shift[jg] = beta[j] - mu * sc;
}

__global__ void alpha_softmax(const float* __restrict__ alpha, float* __restrict__ wsm)
{
    const int idx = threadIdx.x;
    if (idx >= Lnum * Pdim) return;
    const float* a = alpha + idx * Fdim;
    float mx = a[0];
#pragma unroll
    for (int f = 1; f < Fdim; ++f) mx = fmaxf(mx, a[f]);
    float e[Fdim]; float s = 0.f;
#pragma unroll
    for (int f = 0; f < Fdim; ++f) { e[f] = __expf(a[f] - mx); s += e[f]; }
    const float inv = 1.f / s;
#pragma unroll
    for (int f = 0; f < Fdim; ++f) wsm[idx * Fdim + f] = e[f] * inv;
}

// ---------------------------------------------------------------------------
// Fused normalize + gather + combinact, 2 rows/block, E=e^z precomputed at
// staging so the per-pair work needs only {rcp, log, 2 sqrt} transcendentals:
//   sig(z0)*sig(z1) = E0*E1/((1+E0)(1+E1));  lse = LN2*log2(E0+E1).
// LDS: per col f32x4 {z_r0, z_r1, E_r0, E_r1}, bank-swizzled (perm pre-folded).
// MODE 0: grouped planes hg[g][b][p*512+q], c=q*4+g ; MODE 1: flat h[b][p*CH+c]
// ---------------------------------------------------------------------------
template<int MODE>
__global__ __launch_bounds__(256) void combinact_kernel(
    const short* __restrict__ Y, const float* __restrict__ scale,
    const float* __restrict__ shift, const int* __restrict__ perm,
    const float* __restrict__ wsm, short* __restrict__ out)
{
    __shared__ f32x4 zE[Mdim];           // 64 KB
    const int b0  = blockIdx.x * 2;
    const int tid = threadIdx.x;
    const float L2E = 1.44269504f;
    const float LN2 = 0.69314718f;

#pragma unroll
    for (int k = 0; k < 2; ++k) {
        const int i8   = k * 256 + tid;  // 512 chunks of 8 cols
        const int base = i8 * 8;
        const bf16x8 v0 = *((const bf16x8*)(Y + (size_t)(b0 + 0) * Mdim) + i8);
        const bf16x8 v1 = *((const bf16x8*)(Y + (size_t)(b0 + 1) * Mdim) + i8);
        const int xr = i8 & 3;           // bank swizzle: js = j ^ ((j>>3)&3)
#pragma unroll
        for (int jj = 0; jj < 8; ++jj) {
            const float sc = scale[base + jj];
            const float sh = shift[base + jj];
            f32x4 t;
            t[0] = bf2f(v0[jj]) * sc + sh;
            t[1] = bf2f(v1[jj]) * sc + sh;
            t[2] = __builtin_amdgcn_exp2f(L2E * t[0]);
            t[3] = __builtin_amdgcn_exp2f(L2E * t[1]);
            zE[base + (jj ^ xr)] = t;
        }
    }
    __syncthreads();

    float wv[Pdim][Fdim];
#pragma unroll
    for (int p = 0; p < Pdim; ++p)
#pragma unroll
        for (int f = 0; f < Fdim; ++f) wv[p][f] = wsm[p * Fdim + f];

    const size_t plane = (size_t)Bdim * CIN;

#pragma unroll
    for (int k = 0; k < 8; ++k) {
        const int idx = k * 256 + tid;
        int c, g = 0, q = 0;
        if (MODE == 0) { g = idx >> 9; q = idx & 511; c = q * 4 + g; }
        else           { c = idx; }

#pragma unroll
        for (int p = 0; p < Pdim; ++p) {
            const int2 jj = *(const int2*)(perm + p * Mdim + 2 * c);
            const f32x4 c0 = zE[jj.x];
            const f32x4 c1 = zE[jj.y];

#pragma unroll
            for (int r = 0; r < 2; ++r) {
                const float z0 = c0[r],     z1 = c1[r];
                const float E0 = c0[2 + r], E1 = c1[2 + r];

                const float mx = fmaxf(z0, z1);
                const float pr = z0 * z1;
                const float a1 = copysignf(__builtin_amdgcn_sqrtf(fabsf(pr) + 1e-12f), pr);
                const float a2 = z0 * E0 * E1 *
                                 __builtin_amdgcn_rcpf((1.f + E0) * (1.f + E1));
                const float a3 = __builtin_amdgcn_sqrtf(z0 * z0 + z1 * z1 + 1e-12f);
                const float a4 = fmaxf(fabsf(z0), fabsf(z1));
                const float a5 = LN2 * __builtin_amdgcn_logf(E0 + E1);

                const float v = wv[p][0] * mx + wv[p][1] * a1 + wv[p][2] * a2 +
                                wv[p][3] * a3 + wv[p][4] * a4 + wv[p][5] * a5;

                if (MODE == 0)
                    out[g * plane + (size_t)(b0 + r) * CIN + p * 512 + q] = f2bf(v);
                else
                    out[(size_t)(b0 + r) * DNEXT + p * CH + c] = f2bf(v);
            }
        }
    }
}

// ---------------------------------------------------------------------------
extern "C" void kernel_launch(void* const* d_in, const int* in_sizes, int n_in,
                              void* d_out, int out_size, void* d_ws, size_t ws_size,
                              hipStream_t stream)
{
    const float* x     = (const float*)d_in[0];
    const int*   perms = (const int*)  d_in[1];
    const float* W     = (const float*)d_in[2];
    const float* bvec  = (const float*)d_in[3];
    const float* gamma = (const float*)d_in[4];
    const float* beta  = (const float*)d_in[5];
    const float* alpha = (const float*)d_in[6];
    const float* Wo    = (const float*)d_in[7];
    const float* bo    = (const float*)d_in[8];
    float* out = (float*)d_out;

    char* ws = (char*)d_ws;
    short* y      = (short*)ws;                             // B*M bf16 (grouped cols)
    short* hg     = y + (size_t)Bdim * Mdim;                // G*B*CIN bf16 (also hflat)
    float* part   = (float*)(hg + (size_t)Gdim * Bdim * CIN); // 4*B*1024 f32
    float* psum   = part + (size_t)4 * Bdim * 1024;
    float* psumsq = psum + (size_t)NRCHUNK * Mdim;
    float* scale  = psumsq + (size_t)NRCHUNK * Mdim;
    float* shift  = scale + Mdim;
    float* wsm    = shift + Mdim;
    int*   perm_g = (int*)(wsm + Lnum * Pdim * Fdim);       // L*P*M ints

    short* hflat = hg;   // layer-2 combinact output aliases hg (dead then)

    alpha_softmax<<<1, 64, 0, stream>>>(alpha, wsm);
    remap_perms<<<(Lnum * Pdim * Mdim) / 256, 256, 0, stream>>>(
        perms, perm_g, Lnum * Pdim * Mdim);
    x_to_grouped<<<dim3(CIN / 256, Bdim), 256, 0, stream>>>(x, hg);

    const size_t planeA = (size_t)Bdim * CIN;
    const size_t planeB = (size_t)MG * CIN;   // f32 W group stride (elements)

    for (int l = 0; l < Lnum; ++l) {
        // y[b][g*1024+m] bf16, contiguous stores; BN partial stats fused;
        // weights read as f32 directly (reg-staged, converted in-kernel).
        dim3 gg(MG / 128, Bdim / 128, Gdim);
        gemm_mfma<128, 8, true, short><<<gg, 512, 0, stream>>>(
            hg, planeA, CIN,
            W + (size_t)l * Gdim * MG * CIN, planeB, CIN, MG,
            bvec + (size_t)l * Gdim * MG, (size_t)MG,
            y, (size_t)MG,
            CIN, Mdim, MG,
            psum, psumsq, MG);

        bn_finalize<<<Mdim / 256, 256, 0, stream>>>(
            psum, psumsq, gamma + (size_t)l * Mdim, beta + (size_t)l * Mdim, scale, shift);

        if (l < Lnum - 1)
            combinact_kernel<0><<<Bdim / 2, 256, 0, stream>>>(
                y, scale, shift, perm_g + (size_t)l * Pdim * Mdim, wsm + l * Pdim * Fdim, hg);
        else
            combinact_kernel<1><<<Bdim / 2, 256, 0, stream>>>(
                y, scale, shift, perm_g + (size_t)l * Pdim * Mdim, wsm + l * Pdim * Fdim, hflat);
    }

    // Output GEMM, split-K=4 (K=2048 each), Wo read as f32 with row clamp to
    // NOUT (cols >= 1000 computed from dup row, discarded at store).
    dim3 go(1024 / 128, Bdim / 128, 4);
    gemm_mfma<128, 8, false, float><<<go, 512, 0, stream>>>(
        hflat, (size_t)2048, DNEXT,
        Wo, (size_t)2048, DNEXT, NOUT,
        nullptr, 0,
        part, (size_t)Bdim * 1024,
        2048, 1024, 1024,
        nullptr, nullptr, 0);

    dim3 gr(4, Bdim);
    reduce_out<<<gr, 256, 0, stream>>>(part, bo, out);
}

// Round 11
// 304.831 us; speedup vs baseline: 1.2047x; 1.2047x over previous
//
#include <hip/hip_runtime.h>
#include <math.h>

#define Lnum 3
#define Mdim 4096
#define Pdim 4
#define Gdim 4
#define NIN 8192
#define NOUT 1000
#define Bdim 2048
#define Fdim 6
#define CIN 2048      // input channels per group (all layers)
#define MG 1024       // M / G
#define CH 2048       // M / K
#define DNEXT 8192
#define NRCHUNK (Bdim / 128)   // 16 row-blocks of 128 = GEMM tile rows

typedef short bf16x8 __attribute__((ext_vector_type(8)));
typedef float f32x4 __attribute__((ext_vector_type(4)));

__device__ __forceinline__ short f2bf(float f) {
    union { float f; unsigned u; } v; v.f = f;
    unsigned u = v.u;
    unsigned r = (u + 0x7fffu + ((u >> 16) & 1u)) >> 16;
    return (short)r;
}
__device__ __forceinline__ float bf2f(short h) {
    union { unsigned u; float f; } x;
    x.u = ((unsigned)(unsigned short)h) << 16;
    return x.f;
}

// ---------------------------------------------------------------------------
__global__ __launch_bounds__(256) void convert_f32_bf16(
    const float* __restrict__ src, short* __restrict__ dst, int n8)
{
    int i = blockIdx.x * 256 + threadIdx.x;
    if (i >= n8) return;
    const float4* s = (const float4*)src + (size_t)i * 2;
    float4 v0 = s[0], v1 = s[1];
    bf16x8 o;
    o[0] = f2bf(v0.x); o[1] = f2bf(v0.y); o[2] = f2bf(v0.z); o[3] = f2bf(v0.w);
    o[4] = f2bf(v1.x); o[5] = f2bf(v1.y); o[6] = f2bf(v1.z); o[7] = f2bf(v1.w);
    *((bf16x8*)dst + i) = o;
}

// Wo (1000 x 8192) f32 -> padded (1024 x 8192) bf16, pad rows zero
__global__ __launch_bounds__(256) void convert_wo(
    const float* __restrict__ src, short* __restrict__ dst)
{
    int i = blockIdx.x * 256 + threadIdx.x;
    int row = i >> 10;
    bf16x8 o;
    if (row < NOUT) {
        const float4* s = (const float4*)(src + (size_t)row * DNEXT + (i & 1023) * 8);
        float4 v0 = s[0], v1 = s[1];
        o[0] = f2bf(v0.x); o[1] = f2bf(v0.y); o[2] = f2bf(v0.z); o[3] = f2bf(v0.w);
        o[4] = f2bf(v1.x); o[5] = f2bf(v1.y); o[6] = f2bf(v1.z); o[7] = f2bf(v1.w);
    } else {
        for (int j = 0; j < 8; ++j) o[j] = 0;
    }
    *((bf16x8*)dst + i) = o;
}

// x (B x 8192) f32 -> grouped bf16 planes hg[g][b][c] = x[b][4c+g]
__global__ __launch_bounds__(256) void x_to_grouped(
    const float* __restrict__ x, short* __restrict__ hg)
{
    const int c = blockIdx.x * 256 + threadIdx.x;
    const int b = blockIdx.y;
    float4 v = *(const float4*)(x + (size_t)b * NIN + 4 * c);
    const size_t plane = (size_t)Bdim * CIN;
    hg[0 * plane + (size_t)b * CIN + c] = f2bf(v.x);
    hg[1 * plane + (size_t)b * CIN + c] = f2bf(v.y);
    hg[2 * plane + (size_t)b * CIN + c] = f2bf(v.z);
    hg[3 * plane + (size_t)b * CIN + c] = f2bf(v.w);
}

// perm value remap: original j -> grouped col jg = (j&3)*1024 + (j>>2),
// then fold the combinact LDS bank swizzle: js = jg ^ ((jg>>3)&3).
__global__ __launch_bounds__(256) void remap_perms(
    const int* __restrict__ perm, int* __restrict__ perm_g, int n)
{
    int i = blockIdx.x * 256 + threadIdx.x;
    if (i >= n) return;
    int j  = perm[i];
    int jg = ((j & 3) << 10) | (j >> 2);
    perm_g[i] = jg ^ ((jg >> 3) & 3);
}

// ---------------------------------------------------------------------------
// MFMA bf16 GEMM (R8 structure, known-good): both operands bf16 via
// global_load_lds, double-buffered BK=64, XOR-swizzled LDS, counted vmcnt(4).
// Tile 128 x BN_T, 8 waves (2x4). If STATS: fused per-column partial sums ->
// psum/psumsq[by*Mdim + g*sgz + n0 + col] (deterministic, 1 writer/slot).
// ---------------------------------------------------------------------------
template<int BN_T, int NWARP, bool STATS, typename CT>
__global__ __launch_bounds__(NWARP * 64) void gemm_mfma(
    const short* __restrict__ A0, size_t aZ, int lda,
    const short* __restrict__ B0, size_t bZ, int ldb,
    const float* __restrict__ bias0, size_t biasZ,
    CT* __restrict__ C0, size_t cZ,
    int K, int ldc, int nbound,
    float* __restrict__ psum, float* __restrict__ psumsq, int sgz)
{
    constexpr int NT   = NWARP * 64;
    constexpr int WCN  = NWARP / 2;       // waves along N
    constexpr int WCOL = BN_T / WCN;      // cols per wave
    constexpr int FN   = WCOL / 16;       // 16-col frags per wave

    // XCD-aware swizzle (nwg % 8 == 0 in all our launches)
    const int nx = gridDim.x, ny = gridDim.y;
    const int nwg = nx * ny * gridDim.z;
    const int lin = blockIdx.x + nx * (blockIdx.y + ny * blockIdx.z);
    int swz = (lin & 7) * (nwg >> 3) + (lin >> 3);
    const int bx = swz % nx; swz /= nx;
    const int by = swz % ny;
    const int g  = swz / ny;

    const short* A  = A0 + aZ * g;
    const short* Bm = B0 + bZ * g;
    CT* C = C0 + cZ * g;

    const int n0 = bx * BN_T;
    const int b0 = by * 128;

    __shared__ short As[2][128 * 64];
    __shared__ short Bs[2][BN_T * 64];

    const int tid  = threadIdx.x;
    const int w    = tid >> 6;
    const int lane = tid & 63;
    const int wr = w / WCN, wc = w % WCN;

    f32x4 acc[4][FN];
#pragma unroll
    for (int m = 0; m < 4; ++m)
#pragma unroll
        for (int n = 0; n < FN; ++n) acc[m][n] = (f32x4)0.f;

    auto stage = [&](int buf, int k0) {
#pragma unroll
        for (int idx = tid; idx < 128 * 8; idx += NT) {
            const int r = idx >> 3, slot = idx & 7;
            const int gs = slot ^ (r & 7);
            const short* ga = A + (size_t)(b0 + r) * lda + k0 + gs * 8;
            __builtin_amdgcn_global_load_lds(
                (const __attribute__((address_space(1))) void*)ga,
                (__attribute__((address_space(3))) void*)(&As[buf][idx * 8]), 16, 0, 0);
        }
#pragma unroll
        for (int idx = tid; idx < BN_T * 8; idx += NT) {
            const int r = idx >> 3, slot = idx & 7;
            const int gs = slot ^ (r & 7);
            const short* gb = Bm + (size_t)(n0 + r) * ldb + k0 + gs * 8;
            __builtin_amdgcn_global_load_lds(
                (const __attribute__((address_space(1))) void*)gb,
                (__attribute__((address_space(3))) void*)(&Bs[buf][idx * 8]), 16, 0, 0);
        }
    };

    const int fr15 = lane & 15;
    const int fq   = lane >> 4;

    auto compute = [&](int buf) {
#pragma unroll
        for (int kk = 0; kk < 2; ++kk) {
            bf16x8 af[4], bff[FN];
            const int kob = kk * 64 + fq * 16;
#pragma unroll
            for (int m = 0; m < 4; ++m) {
                const int r  = wr * 64 + m * 16 + fr15;
                const int sw = kob ^ ((r & 7) << 4);
                af[m] = *(const bf16x8*)(&As[buf][r * 64 + (sw >> 1)]);
            }
#pragma unroll
            for (int n = 0; n < FN; ++n) {
                const int r  = wc * WCOL + n * 16 + fr15;
                const int sw = kob ^ ((r & 7) << 4);
                bff[n] = *(const bf16x8*)(&Bs[buf][r * 64 + (sw >> 1)]);
            }
#pragma unroll
            for (int m = 0; m < 4; ++m)
#pragma unroll
                for (int n = 0; n < FN; ++n)
                    acc[m][n] = __builtin_amdgcn_mfma_f32_16x16x32_bf16(af[m], bff[n], acc[m][n], 0, 0, 0);
        }
    };

    stage(0, 0);

    const int nt = K >> 6;   // even (K multiple of 128)
    int p = 0;
    for (int t = 0; t < nt - 1; ++t) {
        stage(p ^ 1, (t + 1) << 6);
        asm volatile("s_waitcnt vmcnt(4)" ::: "memory");
        __builtin_amdgcn_s_barrier();
        asm volatile("" ::: "memory");
        compute(p);
        asm volatile("" ::: "memory");
        __builtin_amdgcn_s_barrier();
        p ^= 1;
    }
    asm volatile("s_waitcnt vmcnt(0)" ::: "memory");
    __builtin_amdgcn_s_barrier();
    asm volatile("" ::: "memory");
    compute(p);

    float s[FN], ss[FN];
#pragma unroll
    for (int n = 0; n < FN; ++n) { s[n] = 0.f; ss[n] = 0.f; }

#pragma unroll
    for (int m = 0; m < 4; ++m) {
#pragma unroll
        for (int n = 0; n < FN; ++n) {
#pragma unroll
            for (int j = 0; j < 4; ++j) {
                const int row = b0 + wr * 64 + m * 16 + fq * 4 + j;
                const int col = n0 + wc * WCOL + n * 16 + fr15;
                if (col < nbound) {
                    float v = acc[m][n][j];
                    if (bias0) v += bias0[biasZ * g + col];
                    C[(size_t)row * ldc + col] = (CT)(sizeof(CT) == 2 ? (CT)f2bf(v) : (CT)v);
                    if (STATS) { s[n] += v; ss[n] += v * v; }
                }
            }
        }
    }

    if (STATS) {
        __syncthreads();   // all waves done with LDS compute buffers
        float* sum_lds = (float*)&As[0][0];
        float* ssq_lds = sum_lds + BN_T * 8;
        const int slot = wr * 4 + fq;
#pragma unroll
        for (int n = 0; n < FN; ++n) {
            const int cl = wc * WCOL + n * 16 + fr15;
            sum_lds[cl * 8 + slot] = s[n];
            ssq_lds[cl * 8 + slot] = ss[n];
        }
        __syncthreads();
        for (int cl = tid; cl < BN_T; cl += NT) {
            float a = 0.f, b = 0.f;
#pragma unroll
            for (int q = 0; q < 8; ++q) {
                a += sum_lds[cl * 8 + q];
                b += ssq_lds[cl * 8 + q];
            }
            const size_t o = (size_t)by * Mdim + g * sgz + n0 + cl;
            psum[o]   = a;
            psumsq[o] = b;
        }
    }
}

// out[b,n] = sum_z p[z][b,n] + bo[n], 4 split-K partials
__global__ __launch_bounds__(256) void reduce_out(
    const float* __restrict__ part, const float* __restrict__ bo,
    float* __restrict__ out)
{
    const int n = blockIdx.x * 256 + threadIdx.x;
    const int b = blockIdx.y;
    if (n >= NOUT) return;
    const size_t S = (size_t)Bdim * 1024;
    const size_t i = (size_t)b * 1024 + n;
    out[(size_t)b * NOUT + n] =
        part[i] + part[S + i] + part[2 * S + i] + part[3 * S + i] + bo[n];
}

// ---------------------------------------------------------------------------
// Columns are in GROUPED order jg = g*1024+m  (orig j = (jg&1023)*4 + jg>>10)
__global__ __launch_bounds__(256) void bn_finalize(
    const float* __restrict__ psum, const float* __restrict__ psumsq,
    const float* __restrict__ gamma, const float* __restrict__ beta,
    float* __restrict__ scale, float* __restrict__ shift)
{
    const int jg = blockIdx.x * 256 + threadIdx.x;
    if (jg >= Mdim) return;
    const int j = ((jg & 1023) << 2) | (jg >> 10);
    float s = 0.f, ss = 0.f;
    for (int r = 0; r < NRCHUNK; ++r) {
        s  += psum[r * Mdim + jg];
        ss += psumsq[r * Mdim + jg];
    }
    const float mu  = s * (1.f / Bdim);
    const float var = ss * (1.f / Bdim) - mu * mu;
    const float sc  = gamma[j] * rsqrtf(var + 1e-5f);
    scale[jg] = sc;
    shift[jg] = beta[j] - mu * sc;
}

__global__ void alpha_softmax(const float* __restrict__ alpha, float* __restrict__ wsm)
{
    const int idx = threadIdx.x;
    if (idx >= Lnum * Pdim) return;
    const float* a = alpha + idx * Fdim;
    float mx = a[0];
#pragma unroll
    for (int f = 1; f < Fdim; ++f) mx = fmaxf(mx, a[f]);
    float e[Fdim]; float s = 0.f;
#pragma unroll
    for (int f = 0; f < Fdim; ++f) { e[f] = __expf(a[f] - mx); s += e[f]; }
    const float inv = 1.f / s;
#pragma unroll
    for (int f = 0; f < Fdim; ++f) wsm[idx * Fdim + f] = e[f] * inv;
}

// ---------------------------------------------------------------------------
// Fused normalize + gather + combinact, 2 rows/block, E=e^z precomputed at
// staging so the per-pair work needs only {rcp, log, 2 sqrt} transcendentals:
//   sig(z0)*sig(z1) = E0*E1/((1+E0)(1+E1));  lse = LN2*log2(E0+E1).
// LDS: per col f32x4 {z_r0, z_r1, E_r0, E_r1}, bank-swizzled (perm pre-folded).
// MODE 0: grouped planes hg[g][b][p*512+q], c=q*4+g ; MODE 1: flat h[b][p*CH+c]
// ---------------------------------------------------------------------------
template<int MODE>
__global__ __launch_bounds__(256) void combinact_kernel(
    const short* __restrict__ Y, const float* __restrict__ scale,
    const float* __restrict__ shift, const int* __restrict__ perm,
    const float* __restrict__ wsm, short* __restrict__ out)
{
    __shared__ f32x4 zE[Mdim];           // 64 KB
    const int b0  = blockIdx.x * 2;
    const int tid = threadIdx.x;
    const float L2E = 1.44269504f;
    const float LN2 = 0.69314718f;

#pragma unroll
    for (int k = 0; k < 2; ++k) {
        const int i8   = k * 256 + tid;  // 512 chunks of 8 cols
        const int base = i8 * 8;
        const bf16x8 v0 = *((const bf16x8*)(Y + (size_t)(b0 + 0) * Mdim) + i8);
        const bf16x8 v1 = *((const bf16x8*)(Y + (size_t)(b0 + 1) * Mdim) + i8);
        const int xr = i8 & 3;           // bank swizzle: js = j ^ ((j>>3)&3)
#pragma unroll
        for (int jj = 0; jj < 8; ++jj) {
            const float sc = scale[base + jj];
            const float sh = shift[base + jj];
            f32x4 t;
            t[0] = bf2f(v0[jj]) * sc + sh;
            t[1] = bf2f(v1[jj]) * sc + sh;
            t[2] = __builtin_amdgcn_exp2f(L2E * t[0]);
            t[3] = __builtin_amdgcn_exp2f(L2E * t[1]);
            zE[base + (jj ^ xr)] = t;
        }
    }
    __syncthreads();

    float wv[Pdim][Fdim];
#pragma unroll
    for (int p = 0; p < Pdim; ++p)
#pragma unroll
        for (int f = 0; f < Fdim; ++f) wv[p][f] = wsm[p * Fdim + f];

    const size_t plane = (size_t)Bdim * CIN;

#pragma unroll
    for (int k = 0; k < 8; ++k) {
        const int idx = k * 256 + tid;
        int c, g = 0, q = 0;
        if (MODE == 0) { g = idx >> 9; q = idx & 511; c = q * 4 + g; }
        else           { c = idx; }

#pragma unroll
        for (int p = 0; p < Pdim; ++p) {
            const int2 jj = *(const int2*)(perm + p * Mdim + 2 * c);
            const f32x4 c0 = zE[jj.x];
            const f32x4 c1 = zE[jj.y];

#pragma unroll
            for (int r = 0; r < 2; ++r) {
                const float z0 = c0[r],     z1 = c1[r];
                const float E0 = c0[2 + r], E1 = c1[2 + r];

                const float mx = fmaxf(z0, z1);
                const float pr = z0 * z1;
                const float a1 = copysignf(__builtin_amdgcn_sqrtf(fabsf(pr) + 1e-12f), pr);
                const float a2 = z0 * E0 * E1 *
                                 __builtin_amdgcn_rcpf((1.f + E0) * (1.f + E1));
                const float a3 = __builtin_amdgcn_sqrtf(z0 * z0 + z1 * z1 + 1e-12f);
                const float a4 = fmaxf(fabsf(z0), fabsf(z1));
                const float a5 = LN2 * __builtin_amdgcn_logf(E0 + E1);

                const float v = wv[p][0] * mx + wv[p][1] * a1 + wv[p][2] * a2 +
                                wv[p][3] * a3 + wv[p][4] * a4 + wv[p][5] * a5;

                if (MODE == 0)
                    out[g * plane + (size_t)(b0 + r) * CIN + p * 512 + q] = f2bf(v);
                else
                    out[(size_t)(b0 + r) * DNEXT + p * CH + c] = f2bf(v);
            }
        }
    }
}

// ---------------------------------------------------------------------------
extern "C" void kernel_launch(void* const* d_in, const int* in_sizes, int n_in,
                              void* d_out, int out_size, void* d_ws, size_t ws_size,
                              hipStream_t stream)
{
    const float* x     = (const float*)d_in[0];
    const int*   perms = (const int*)  d_in[1];
    const float* W     = (const float*)d_in[2];
    const float* bvec  = (const float*)d_in[3];
    const float* gamma = (const float*)d_in[4];
    const float* beta  = (const float*)d_in[5];
    const float* alpha = (const float*)d_in[6];
    const float* Wo    = (const float*)d_in[7];
    const float* bo    = (const float*)d_in[8];
    float* out = (float*)d_out;

    char* ws = (char*)d_ws;
    short* y      = (short*)ws;                             // B*M bf16 (grouped cols)
    short* hg     = y + (size_t)Bdim * Mdim;                // G*B*CIN bf16 (also hflat)
    short* Wlb3   = hg + (size_t)Gdim * Bdim * CIN;         // 3*G*MG*CIN bf16 (all layers)
    short* Wob    = Wlb3 + (size_t)Lnum * Gdim * MG * CIN;  // 1024*8192 bf16
    float* psum   = (float*)(Wob + (size_t)1024 * DNEXT);
    float* psumsq = psum + (size_t)NRCHUNK * Mdim;
    float* scale  = psumsq + (size_t)NRCHUNK * Mdim;
    float* shift  = scale + Mdim;
    float* wsm    = shift + Mdim;
    int*   perm_g = (int*)(wsm + Lnum * Pdim * Fdim);       // L*P*M ints

    short* hflat = hg;           // layer-2 combinact output aliases hg (dead then)
    float* part  = (float*)Wlb3; // out-GEMM partials alias Wlb3 (dead then), 32 MB

    alpha_softmax<<<1, 64, 0, stream>>>(alpha, wsm);
    remap_perms<<<(Lnum * Pdim * Mdim) / 256, 256, 0, stream>>>(
        perms, perm_g, Lnum * Pdim * Mdim);
    convert_f32_bf16<<<(Lnum * Gdim * MG * CIN / 8) / 256, 256, 0, stream>>>(
        W, Wlb3, Lnum * Gdim * MG * CIN / 8);
    convert_wo<<<(1024 * 1024) / 256, 256, 0, stream>>>(Wo, Wob);
    x_to_grouped<<<dim3(CIN / 256, Bdim), 256, 0, stream>>>(x, hg);

    const size_t planeA = (size_t)Bdim * CIN;
    const size_t planeB = (size_t)MG * CIN;

    for (int l = 0; l < Lnum; ++l) {
        // y[b][g*1024+m] bf16, contiguous stores; BN partial stats fused.
        dim3 gg(MG / 128, Bdim / 128, Gdim);
        gemm_mfma<128, 8, true, short><<<gg, 512, 0, stream>>>(
            hg, planeA, CIN, Wlb3 + (size_t)l * Gdim * MG * CIN, planeB, CIN,
            bvec + (size_t)l * Gdim * MG, (size_t)MG,
            y, (size_t)MG,
            CIN, Mdim, MG,
            psum, psumsq, MG);

        bn_finalize<<<Mdim / 256, 256, 0, stream>>>(
            psum, psumsq, gamma + (size_t)l * Mdim, beta + (size_t)l * Mdim, scale, shift);

        if (l < Lnum - 1)
            combinact_kernel<0><<<Bdim / 2, 256, 0, stream>>>(
                y, scale, shift, perm_g + (size_t)l * Pdim * Mdim, wsm + l * Pdim * Fdim, hg);
        else
            combinact_kernel<1><<<Bdim / 2, 256, 0, stream>>>(
                y, scale, shift, perm_g + (size_t)l * Pdim * Mdim, wsm + l * Pdim * Fdim, hflat);
    }

    // Output GEMM, split-K=4 (K=2048 each), partials in Wlb3 region, then reduce.
    dim3 go(1024 / 128, Bdim / 128, 4);
    gemm_mfma<128, 8, false, float><<<go, 512, 0, stream>>>(
        hflat, (size_t)2048, DNEXT, Wob, (size_t)2048, DNEXT,
        nullptr, 0,
        part, (size_t)Bdim * 1024,
        2048, 1024, 1024,
        nullptr, nullptr, 0);

    dim3 gr(4, Bdim);
    reduce_out<<<gr, 256, 0, stream>>>(part, bo, out);
}

// Round 12
// 299.082 us; speedup vs baseline: 1.2278x; 1.0192x over previous
//
#include <hip/hip_runtime.h>
#include <math.h>

#define Lnum 3
#define Mdim 4096
#define Pdim 4
#define Gdim 4
#define NIN 8192
#define NOUT 1000
#define Bdim 2048
#define Fdim 6
#define CIN 2048      // input channels per group (all layers)
#define MG 1024       // M / G
#define CH 2048       // M / K
#define DNEXT 8192
#define NRCHUNK (Bdim / 128)   // 16 row-blocks of 128 = GEMM tile rows

typedef short bf16x8 __attribute__((ext_vector_type(8)));
typedef float f32x4 __attribute__((ext_vector_type(4)));

__device__ __forceinline__ short f2bf(float f) {
    union { float f; unsigned u; } v; v.f = f;
    unsigned u = v.u;
    unsigned r = (u + 0x7fffu + ((u >> 16) & 1u)) >> 16;
    return (short)r;
}
__device__ __forceinline__ float bf2f(short h) {
    union { unsigned u; float f; } x;
    x.u = ((unsigned)(unsigned short)h) << 16;
    return x.f;
}

// ---------------------------------------------------------------------------
__global__ __launch_bounds__(256) void convert_f32_bf16(
    const float* __restrict__ src, short* __restrict__ dst, int n8)
{
    int i = blockIdx.x * 256 + threadIdx.x;
    if (i >= n8) return;
    const float4* s = (const float4*)src + (size_t)i * 2;
    float4 v0 = s[0], v1 = s[1];
    bf16x8 o;
    o[0] = f2bf(v0.x); o[1] = f2bf(v0.y); o[2] = f2bf(v0.z); o[3] = f2bf(v0.w);
    o[4] = f2bf(v1.x); o[5] = f2bf(v1.y); o[6] = f2bf(v1.z); o[7] = f2bf(v1.w);
    *((bf16x8*)dst + i) = o;
}

// Wo (1000 x 8192) f32 -> padded (1024 x 8192) bf16, pad rows zero
__global__ __launch_bounds__(256) void convert_wo(
    const float* __restrict__ src, short* __restrict__ dst)
{
    int i = blockIdx.x * 256 + threadIdx.x;
    int row = i >> 10;
    bf16x8 o;
    if (row < NOUT) {
        const float4* s = (const float4*)(src + (size_t)row * DNEXT + (i & 1023) * 8);
        float4 v0 = s[0], v1 = s[1];
        o[0] = f2bf(v0.x); o[1] = f2bf(v0.y); o[2] = f2bf(v0.z); o[3] = f2bf(v0.w);
        o[4] = f2bf(v1.x); o[5] = f2bf(v1.y); o[6] = f2bf(v1.z); o[7] = f2bf(v1.w);
    } else {
        for (int j = 0; j < 8; ++j) o[j] = 0;
    }
    *((bf16x8*)dst + i) = o;
}

// x (B x 8192) f32 -> grouped bf16 planes hg[g][b][c] = x[b][4c+g]
__global__ __launch_bounds__(256) void x_to_grouped(
    const float* __restrict__ x, short* __restrict__ hg)
{
    const int c = blockIdx.x * 256 + threadIdx.x;
    const int b = blockIdx.y;
    float4 v = *(const float4*)(x + (size_t)b * NIN + 4 * c);
    const size_t plane = (size_t)Bdim * CIN;
    hg[0 * plane + (size_t)b * CIN + c] = f2bf(v.x);
    hg[1 * plane + (size_t)b * CIN + c] = f2bf(v.y);
    hg[2 * plane + (size_t)b * CIN + c] = f2bf(v.z);
    hg[3 * plane + (size_t)b * CIN + c] = f2bf(v.w);
}

// perm value remap: original j -> grouped col jg = (j&3)*1024 + (j>>2),
// then fold the combinact LDS bank swizzle: js = jg ^ ((jg>>3)&3).
__global__ __launch_bounds__(256) void remap_perms(
    const int* __restrict__ perm, int* __restrict__ perm_g, int n)
{
    int i = blockIdx.x * 256 + threadIdx.x;
    if (i >= n) return;
    int j  = perm[i];
    int jg = ((j & 3) << 10) | (j >> 2);
    perm_g[i] = jg ^ ((jg >> 3) & 3);
}

// ---------------------------------------------------------------------------
// MFMA bf16 GEMM (R8 structure, known-good): both operands bf16 via
// global_load_lds, double-buffered BK=64, XOR-swizzled LDS, counted vmcnt(4).
// Tile 128 x BN_T, 8 waves (2x4). If STATS: fused per-column partial sums ->
// psum/psumsq[by*Mdim + g*sgz + n0 + col] (deterministic, 1 writer/slot).
// ---------------------------------------------------------------------------
template<int BN_T, int NWARP, bool STATS, typename CT>
__global__ __launch_bounds__(NWARP * 64) void gemm_mfma(
    const short* __restrict__ A0, size_t aZ, int lda,
    const short* __restrict__ B0, size_t bZ, int ldb,
    const float* __restrict__ bias0, size_t biasZ,
    CT* __restrict__ C0, size_t cZ,
    int K, int ldc, int nbound,
    float* __restrict__ psum, float* __restrict__ psumsq, int sgz)
{
    constexpr int NT   = NWARP * 64;
    constexpr int WCN  = NWARP / 2;       // waves along N
    constexpr int WCOL = BN_T / WCN;      // cols per wave
    constexpr int FN   = WCOL / 16;       // 16-col frags per wave

    // XCD-aware swizzle (nwg % 8 == 0 in all our launches)
    const int nx = gridDim.x, ny = gridDim.y;
    const int nwg = nx * ny * gridDim.z;
    const int lin = blockIdx.x + nx * (blockIdx.y + ny * blockIdx.z);
    int swz = (lin & 7) * (nwg >> 3) + (lin >> 3);
    const int bx = swz % nx; swz /= nx;
    const int by = swz % ny;
    const int g  = swz / ny;

    const short* A  = A0 + aZ * g;
    const short* Bm = B0 + bZ * g;
    CT* C = C0 + cZ * g;

    const int n0 = bx * BN_T;
    const int b0 = by * 128;

    __shared__ short As[2][128 * 64];
    __shared__ short Bs[2][BN_T * 64];

    const int tid  = threadIdx.x;
    const int w    = tid >> 6;
    const int lane = tid & 63;
    const int wr = w / WCN, wc = w % WCN;

    f32x4 acc[4][FN];
#pragma unroll
    for (int m = 0; m < 4; ++m)
#pragma unroll
        for (int n = 0; n < FN; ++n) acc[m][n] = (f32x4)0.f;

    auto stage = [&](int buf, int k0) {
#pragma unroll
        for (int idx = tid; idx < 128 * 8; idx += NT) {
            const int r = idx >> 3, slot = idx & 7;
            const int gs = slot ^ (r & 7);
            const short* ga = A + (size_t)(b0 + r) * lda + k0 + gs * 8;
            __builtin_amdgcn_global_load_lds(
                (const __attribute__((address_space(1))) void*)ga,
                (__attribute__((address_space(3))) void*)(&As[buf][idx * 8]), 16, 0, 0);
        }
#pragma unroll
        for (int idx = tid; idx < BN_T * 8; idx += NT) {
            const int r = idx >> 3, slot = idx & 7;
            const int gs = slot ^ (r & 7);
            const short* gb = Bm + (size_t)(n0 + r) * ldb + k0 + gs * 8;
            __builtin_amdgcn_global_load_lds(
                (const __attribute__((address_space(1))) void*)gb,
                (__attribute__((address_space(3))) void*)(&Bs[buf][idx * 8]), 16, 0, 0);
        }
    };

    const int fr15 = lane & 15;
    const int fq   = lane >> 4;

    auto compute = [&](int buf) {
#pragma unroll
        for (int kk = 0; kk < 2; ++kk) {
            bf16x8 af[4], bff[FN];
            const int kob = kk * 64 + fq * 16;
#pragma unroll
            for (int m = 0; m < 4; ++m) {
                const int r  = wr * 64 + m * 16 + fr15;
                const int sw = kob ^ ((r & 7) << 4);
                af[m] = *(const bf16x8*)(&As[buf][r * 64 + (sw >> 1)]);
            }
#pragma unroll
            for (int n = 0; n < FN; ++n) {
                const int r  = wc * WCOL + n * 16 + fr15;
                const int sw = kob ^ ((r & 7) << 4);
                bff[n] = *(const bf16x8*)(&Bs[buf][r * 64 + (sw >> 1)]);
            }
#pragma unroll
            for (int m = 0; m < 4; ++m)
#pragma unroll
                for (int n = 0; n < FN; ++n)
                    acc[m][n] = __builtin_amdgcn_mfma_f32_16x16x32_bf16(af[m], bff[n], acc[m][n], 0, 0, 0);
        }
    };

    stage(0, 0);

    const int nt = K >> 6;   // even (K multiple of 128)
    int p = 0;
    for (int t = 0; t < nt - 1; ++t) {
        stage(p ^ 1, (t + 1) << 6);
        asm volatile("s_waitcnt vmcnt(4)" ::: "memory");
        __builtin_amdgcn_s_barrier();
        asm volatile("" ::: "memory");
        compute(p);
        asm volatile("" ::: "memory");
        __builtin_amdgcn_s_barrier();
        p ^= 1;
    }
    asm volatile("s_waitcnt vmcnt(0)" ::: "memory");
    __builtin_amdgcn_s_barrier();
    asm volatile("" ::: "memory");
    compute(p);

    float s[FN], ss[FN];
#pragma unroll
    for (int n = 0; n < FN; ++n) { s[n] = 0.f; ss[n] = 0.f; }

#pragma unroll
    for (int m = 0; m < 4; ++m) {
#pragma unroll
        for (int n = 0; n < FN; ++n) {
#pragma unroll
            for (int j = 0; j < 4; ++j) {
                const int row = b0 + wr * 64 + m * 16 + fq * 4 + j;
                const int col = n0 + wc * WCOL + n * 16 + fr15;
                if (col < nbound) {
                    float v = acc[m][n][j];
                    if (bias0) v += bias0[biasZ * g + col];
                    C[(size_t)row * ldc + col] = (CT)(sizeof(CT) == 2 ? (CT)f2bf(v) : (CT)v);
                    if (STATS) { s[n] += v; ss[n] += v * v; }
                }
            }
        }
    }

    if (STATS) {
        __syncthreads();   // all waves done with LDS compute buffers
        float* sum_lds = (float*)&As[0][0];
        float* ssq_lds = sum_lds + BN_T * 8;
        const int slot = wr * 4 + fq;
#pragma unroll
        for (int n = 0; n < FN; ++n) {
            const int cl = wc * WCOL + n * 16 + fr15;
            sum_lds[cl * 8 + slot] = s[n];
            ssq_lds[cl * 8 + slot] = ss[n];
        }
        __syncthreads();
        for (int cl = tid; cl < BN_T; cl += NT) {
            float a = 0.f, b = 0.f;
#pragma unroll
            for (int q = 0; q < 8; ++q) {
                a += sum_lds[cl * 8 + q];
                b += ssq_lds[cl * 8 + q];
            }
            const size_t o = (size_t)by * Mdim + g * sgz + n0 + cl;
            psum[o]   = a;
            psumsq[o] = b;
        }
    }
}

// out[b,n] = sum_z p[z][b,n] + bo[n], 4 split-K partials
__global__ __launch_bounds__(256) void reduce_out(
    const float* __restrict__ part, const float* __restrict__ bo,
    float* __restrict__ out)
{
    const int n = blockIdx.x * 256 + threadIdx.x;
    const int b = blockIdx.y;
    if (n >= NOUT) return;
    const size_t S = (size_t)Bdim * 1024;
    const size_t i = (size_t)b * 1024 + n;
    out[(size_t)b * NOUT + n] =
        part[i] + part[S + i] + part[2 * S + i] + part[3 * S + i] + bo[n];
}

// ---------------------------------------------------------------------------
// Columns are in GROUPED order jg = g*1024+m  (orig j = (jg&1023)*4 + jg>>10)
__global__ __launch_bounds__(256) void bn_finalize(
    const float* __restrict__ psum, const float* __restrict__ psumsq,
    const float* __restrict__ gamma, const float* __restrict__ beta,
    float* __restrict__ scale, float* __restrict__ shift)
{
    const int jg = blockIdx.x * 256 + threadIdx.x;
    if (jg >= Mdim) return;
    const int j = ((jg & 1023) << 2) | (jg >> 10);
    float s = 0.f, ss = 0.f;
    for (int r = 0; r < NRCHUNK; ++r) {
        s  += psum[r * Mdim + jg];
        ss += psumsq[r * Mdim + jg];
    }
    const float mu  = s * (1.f / Bdim);
    const float var = ss * (1.f / Bdim) - mu * mu;
    const float sc  = gamma[j] * rsqrtf(var + 1e-5f);
    scale[jg] = sc;
    shift[jg] = beta[j] - mu * sc;
}

__global__ void alpha_softmax(const float* __restrict__ alpha, float* __restrict__ wsm)
{
    const int idx = threadIdx.x;
    if (idx >= Lnum * Pdim) return;
    const float* a = alpha + idx * Fdim;
    float mx = a[0];
#pragma unroll
    for (int f = 1; f < Fdim; ++f) mx = fmaxf(mx, a[f]);
    float e[Fdim]; float s = 0.f;
#pragma unroll
    for (int f = 0; f < Fdim; ++f) { e[f] = __expf(a[f] - mx); s += e[f]; }
    const float inv = 1.f / s;
#pragma unroll
    for (int f = 0; f < Fdim; ++f) wsm[idx * Fdim + f] = e[f] * inv;
}

// ---------------------------------------------------------------------------
// Fused normalize + gather + combinact, 2 rows/block, 512 threads (8 waves)
// for 16 waves/CU occupancy. E=e^z precomputed at staging:
//   sig(z0)*sig(z1) = E0*E1/((1+E0)(1+E1));  lse = LN2*log2(E0+E1).
// LDS: per col f32x4 {z_r0, z_r1, E_r0, E_r1}, bank-swizzled (perm pre-folded).
// MODE 0: grouped planes hg[g][b][p*512+q], c=q*4+g ; MODE 1: flat h[b][p*CH+c]
// ---------------------------------------------------------------------------
template<int MODE>
__global__ __launch_bounds__(512) void combinact_kernel(
    const short* __restrict__ Y, const float* __restrict__ scale,
    const float* __restrict__ shift, const int* __restrict__ perm,
    const float* __restrict__ wsm, short* __restrict__ out)
{
    __shared__ f32x4 zE[Mdim];           // 64 KB
    const int b0  = blockIdx.x * 2;
    const int tid = threadIdx.x;
    const float L2E = 1.44269504f;
    const float LN2 = 0.69314718f;

    {
        const int i8   = tid;            // 512 chunks of 8 cols, 1 per thread
        const int base = i8 * 8;
        const bf16x8 v0 = *((const bf16x8*)(Y + (size_t)(b0 + 0) * Mdim) + i8);
        const bf16x8 v1 = *((const bf16x8*)(Y + (size_t)(b0 + 1) * Mdim) + i8);
        const int xr = i8 & 3;           // bank swizzle: js = j ^ ((j>>3)&3)
#pragma unroll
        for (int jj = 0; jj < 8; ++jj) {
            const float sc = scale[base + jj];
            const float sh = shift[base + jj];
            f32x4 t;
            t[0] = bf2f(v0[jj]) * sc + sh;
            t[1] = bf2f(v1[jj]) * sc + sh;
            t[2] = __builtin_amdgcn_exp2f(L2E * t[0]);
            t[3] = __builtin_amdgcn_exp2f(L2E * t[1]);
            zE[base + (jj ^ xr)] = t;
        }
    }
    __syncthreads();

    float wv[Pdim][Fdim];
#pragma unroll
    for (int p = 0; p < Pdim; ++p)
#pragma unroll
        for (int f = 0; f < Fdim; ++f) wv[p][f] = wsm[p * Fdim + f];

    const size_t plane = (size_t)Bdim * CIN;

#pragma unroll
    for (int k = 0; k < 4; ++k) {
        const int idx = k * 512 + tid;
        int c, g = 0, q = 0;
        if (MODE == 0) { g = idx >> 9; q = idx & 511; c = q * 4 + g; }
        else           { c = idx; }

#pragma unroll
        for (int p = 0; p < Pdim; ++p) {
            const int2 jj = *(const int2*)(perm + p * Mdim + 2 * c);
            const f32x4 c0 = zE[jj.x];
            const f32x4 c1 = zE[jj.y];

#pragma unroll
            for (int r = 0; r < 2; ++r) {
                const float z0 = c0[r],     z1 = c1[r];
                const float E0 = c0[2 + r], E1 = c1[2 + r];

                const float mx = fmaxf(z0, z1);
                const float pr = z0 * z1;
                const float a1 = copysignf(__builtin_amdgcn_sqrtf(fabsf(pr) + 1e-12f), pr);
                const float a2 = z0 * E0 * E1 *
                                 __builtin_amdgcn_rcpf((1.f + E0) * (1.f + E1));
                const float a3 = __builtin_amdgcn_sqrtf(z0 * z0 + z1 * z1 + 1e-12f);
                const float a4 = fmaxf(fabsf(z0), fabsf(z1));
                const float a5 = LN2 * __builtin_amdgcn_logf(E0 + E1);

                const float v = wv[p][0] * mx + wv[p][1] * a1 + wv[p][2] * a2 +
                                wv[p][3] * a3 + wv[p][4] * a4 + wv[p][5] * a5;

                if (MODE == 0)
                    out[g * plane + (size_t)(b0 + r) * CIN + p * 512 + q] = f2bf(v);
                else
                    out[(size_t)(b0 + r) * DNEXT + p * CH + c] = f2bf(v);
            }
        }
    }
}

// ---------------------------------------------------------------------------
extern "C" void kernel_launch(void* const* d_in, const int* in_sizes, int n_in,
                              void* d_out, int out_size, void* d_ws, size_t ws_size,
                              hipStream_t stream)
{
    const float* x     = (const float*)d_in[0];
    const int*   perms = (const int*)  d_in[1];
    const float* W     = (const float*)d_in[2];
    const float* bvec  = (const float*)d_in[3];
    const float* gamma = (const float*)d_in[4];
    const float* beta  = (const float*)d_in[5];
    const float* alpha = (const float*)d_in[6];
    const float* Wo    = (const float*)d_in[7];
    const float* bo    = (const float*)d_in[8];
    float* out = (float*)d_out;

    char* ws = (char*)d_ws;
    short* y      = (short*)ws;                             // B*M bf16 (grouped cols)
    short* hg     = y + (size_t)Bdim * Mdim;                // G*B*CIN bf16 (also hflat)
    short* Wlb3   = hg + (size_t)Gdim * Bdim * CIN;         // 3*G*MG*CIN bf16 (all layers)
    short* Wob    = Wlb3 + (size_t)Lnum * Gdim * MG * CIN;  // 1024*8192 bf16
    float* psum   = (float*)(Wob + (size_t)1024 * DNEXT);
    float* psumsq = psum + (size_t)NRCHUNK * Mdim;
    float* scale  = psumsq + (size_t)NRCHUNK * Mdim;
    float* shift  = scale + Mdim;
    float* wsm    = shift + Mdim;
    int*   perm_g = (int*)(wsm + Lnum * Pdim * Fdim);       // L*P*M ints

    short* hflat = hg;           // layer-2 combinact output aliases hg (dead then)
    float* part  = (float*)Wlb3; // out-GEMM partials alias Wlb3 (dead then), 32 MB

    alpha_softmax<<<1, 64, 0, stream>>>(alpha, wsm);
    remap_perms<<<(Lnum * Pdim * Mdim) / 256, 256, 0, stream>>>(
        perms, perm_g, Lnum * Pdim * Mdim);
    convert_f32_bf16<<<(Lnum * Gdim * MG * CIN / 8) / 256, 256, 0, stream>>>(
        W, Wlb3, Lnum * Gdim * MG * CIN / 8);
    convert_wo<<<(1024 * 1024) / 256, 256, 0, stream>>>(Wo, Wob);
    x_to_grouped<<<dim3(CIN / 256, Bdim), 256, 0, stream>>>(x, hg);

    const size_t planeA = (size_t)Bdim * CIN;
    const size_t planeB = (size_t)MG * CIN;

    for (int l = 0; l < Lnum; ++l) {
        // y[b][g*1024+m] bf16, contiguous stores; BN partial stats fused.
        dim3 gg(MG / 128, Bdim / 128, Gdim);
        gemm_mfma<128, 8, true, short><<<gg, 512, 0, stream>>>(
            hg, planeA, CIN, Wlb3 + (size_t)l * Gdim * MG * CIN, planeB, CIN,
            bvec + (size_t)l * Gdim * MG, (size_t)MG,
            y, (size_t)MG,
            CIN, Mdim, MG,
            psum, psumsq, MG);

        bn_finalize<<<Mdim / 256, 256, 0, stream>>>(
            psum, psumsq, gamma + (size_t)l * Mdim, beta + (size_t)l * Mdim, scale, shift);

        if (l < Lnum - 1)
            combinact_kernel<0><<<Bdim / 2, 512, 0, stream>>>(
                y, scale, shift, perm_g + (size_t)l * Pdim * Mdim, wsm + l * Pdim * Fdim, hg);
        else
            combinact_kernel<1><<<Bdim / 2, 512, 0, stream>>>(
                y, scale, shift, perm_g + (size_t)l * Pdim * Mdim, wsm + l * Pdim * Fdim, hflat);
    }

    // Output GEMM, split-K=4 (K=2048 each), partials in Wlb3 region, then reduce.
    dim3 go(1024 / 128, Bdim / 128, 4);
    gemm_mfma<128, 8, false, float><<<go, 512, 0, stream>>>(
        hflat, (size_t)2048, DNEXT, Wob, (size_t)2048, DNEXT,
        nullptr, 0,
        part, (size_t)Bdim * 1024,
        2048, 1024, 1024,
        nullptr, nullptr, 0);

    dim3 gr(4, Bdim);
    reduce_out<<<gr, 256, 0, stream>>>(part, bo, out);
}